// Round 5
// baseline (73.510 us; speedup 1.0000x reference)
//
#include <hip/hip_runtime.h>

#define HH 128
#define WW 128
#define HWSZ (HH*WW)
#define NB 4
#define CIN 64
#define COUT 64
#define KK 9
#define XSTR 96   // NHWC channel stride in bf16 elements (192 B): c0-63 input, c64 mask, c65-95 zero

typedef short bf16x8 __attribute__((ext_vector_type(8)));
typedef float f32x4 __attribute__((ext_vector_type(4)));

union U4 { uint4 v; unsigned a[4]; };

__device__ __forceinline__ short f2bf(float f) {
    union { float f; unsigned u; } v; v.f = f;
    unsigned r = v.u + 0x7FFFu + ((v.u >> 16) & 1u);
    return (short)(r >> 16);
}
__device__ __forceinline__ float bflo(unsigned dw) {
    union { unsigned u; float f; } v; v.u = dw << 16; return v.f;
}
__device__ __forceinline__ float bfhi(unsigned dw) {
    union { unsigned u; float f; } v; v.u = dw & 0xFFFF0000u; return v.f;
}
__device__ __forceinline__ unsigned cvtpk(float lo, float hi) {
    unsigned r;
    asm("v_cvt_pk_bf16_f32 %0, %1, %2" : "=v"(r) : "v"(lo), "v"(hi));
    return r;
}

// ---------------- prep: NHWC-bf16 transpose (blocks 0..1023) + weight repack ----------------
// xt: [NB*HWSZ][96] bf16: c0-63 input, c64 = mask_in (bf16 exact 0/1), c65-95 = 0
// wd: deform B frags [(tap*2+ks)*4+nt][64][8]   (36864 bf16)
// wc: conv   B frags [(tap*3+ks)*2+nt][64][8]   (27648 bf16), ks=2 holds mask channel c=64
__global__ __launch_bounds__(256) void prep_kernel(
    const float* __restrict__ input,
    const float* __restrict__ mask_in,
    const float* __restrict__ weight,
    const float* __restrict__ offset_w,
    const float* __restrict__ mask_w,
    short* __restrict__ xt,
    short* __restrict__ wd,
    short* __restrict__ wc)
{
    __shared__ short lds[64 * 102];
    int bid = blockIdx.x;
    if (bid < 1024) {
        int g0 = bid * 64;
        int b  = g0 >> 14;
        int p0 = g0 & (HWSZ - 1);
        int px = threadIdx.x & 63;
        int cq = threadIdx.x >> 6;
#pragma unroll
        for (int it = 0; it < 24; ++it) {
            int c = it * 4 + cq;
            float v;
            if (c < 64)       v = input[((size_t)(b * 64 + c)) * HWSZ + p0 + px];
            else if (c == 64) v = mask_in[(size_t)b * HWSZ + p0 + px];
            else              v = 0.f;
            lds[px * 102 + c] = f2bf(v);
        }
        __syncthreads();
#pragma unroll
        for (int it = 0; it < 3; ++it) {
            int idx = it * 256 + threadIdx.x;
            if (idx < 768) {
                int ppx = idx / 12, s = idx - ppx * 12;
                bf16x8 v = *(const bf16x8*)&lds[ppx * 102 + s * 8];
                *(bf16x8*)&xt[((size_t)(g0 + ppx)) * XSTR + s * 8] = v;
            }
        }
    } else {
        int idx = (bid - 1024) * 256 + threadIdx.x;   // 0..36863
        if (idx < 36864) {
            int j  = idx & 7;
            int l  = (idx >> 3) & 63;
            int nt = (idx >> 9) & 3;
            int ks = (idx >> 11) & 1;
            int tap = idx >> 12;
            int o = nt * 16 + (l & 15);
            int c = ks * 32 + ((l >> 4) & 3) * 8 + j;
            wd[idx] = f2bf(weight[(o * 64 + c) * 9 + tap]);
        }
        if (idx < 27648) {
            int j  = idx & 7;
            int l  = (idx >> 3) & 63;
            int nt = (idx >> 9) & 1;
            int tks = idx >> 10;              // 0..26
            int tap = tks / 3, ks = tks - tap * 3;
            int o = nt * 16 + (l & 15);
            int c = ks * 32 + ((l >> 4) & 3) * 8 + j;   // ks=2 -> 64 + lg*8 + j
            float v = 0.f;
            if (c <= 64) {
                if (o < 18)      v = offset_w[(o * 65 + c) * 9 + tap];
                else if (o < 27) v = mask_w[((o - 18) * 65 + c) * 9 + tap];
            }
            wc[idx] = f2bf(v);
        }
    }
}

// ---------------- conv (65ch in, 27ch out, 3x3, pad 1) pure MFMA, pixel-major output ----------------
// off_px: [NB*HWSZ][32] f32: slots 0..17 offsets (dy/dx interleaved), 18..26 sigmoid(mask), 27..31 pad
__global__ __launch_bounds__(256, 4) void conv_offset_mfma(
    const short* __restrict__ xt, const bf16x8* __restrict__ wc,
    const float* __restrict__ offset_b, const float* __restrict__ mask_b,
    float* __restrict__ off_px)
{
    int wid = threadIdx.x >> 6;
    int lane = threadIdx.x & 63;
    int r = lane & 15, lg = lane >> 4;
    int g0 = blockIdx.x * 64 + wid * 16;
    int gp = g0 + r;
    int b = gp >> 14, p = gp & (HWSZ - 1);
    int i = p >> 7, j = p & 127;
    const short* xb = xt + ((size_t)(b << 14)) * XSTR + lg * 8;

    f32x4 acc0 = {0,0,0,0}, acc1 = {0,0,0,0};
    U4 a[2][3];
    bool vbuf[2];

#define CSTATE(T, TB) do {                                                    \
        int yy = i + (T) / 3 - 1, xx = j + (T) % 3 - 1;                       \
        bool v = ((unsigned)yy < HH) && ((unsigned)xx < WW);                  \
        int nb = (v ? (yy * WW + xx) : 0) * XSTR;                             \
        vbuf[TB] = v;                                                         \
        a[TB][0].v = *(const uint4*)(xb + nb);                                \
        a[TB][1].v = *(const uint4*)(xb + nb + 32);                           \
        a[TB][2].v = *(const uint4*)(xb + nb + 64);                           \
    } while (0)

    CSTATE(0, 0);
#pragma unroll
    for (int t = 0; t < 9; ++t) {
        int tb = t & 1;
        if (t < 8) CSTATE(t + 1, (t + 1) & 1);
        const bf16x8* wck = wc + (t * 6) * 64 + lane;
#pragma unroll
        for (int ks = 0; ks < 3; ++ks) {
            union { bf16x8 s8; uint4 u; } A;
            A.u = a[tb][ks].v;
            if (!vbuf[tb]) { A.u.x = 0; A.u.y = 0; A.u.z = 0; A.u.w = 0; }
            bf16x8 B0 = wck[(ks * 2 + 0) * 64];
            bf16x8 B1 = wck[(ks * 2 + 1) * 64];
            acc0 = __builtin_amdgcn_mfma_f32_16x16x32_bf16(A.s8, B0, acc0, 0, 0, 0);
            acc1 = __builtin_amdgcn_mfma_f32_16x16x32_bf16(A.s8, B1, acc1, 0, 0, 0);
        }
    }
#undef CSTATE

    int oc = lane & 15, pr0 = lg * 4;
#pragma unroll
    for (int rr = 0; rr < 4; ++rr) {
        int gpix = g0 + pr0 + rr;
        float* orow = off_px + (size_t)gpix * 32;
        orow[oc] = acc0[rr] + offset_b[oc];
        int oc2 = 16 + oc;
        if (oc2 < 18) {
            orow[oc2] = acc1[rr] + offset_b[oc2];
        } else if (oc2 < 27) {
            float z = acc1[rr] + mask_b[oc2 - 18];
            orow[oc2] = 1.f / (1.f + __expf(-z));
        }
    }
}

// ---------------- main deformable conv: pipelined MFMA + fused update_mask ----------------
__global__ __launch_bounds__(256, 4) void deform_main_mfma(
    const short* __restrict__ xt, const float* __restrict__ off_px,
    const float* __restrict__ mask_in, const bf16x8* __restrict__ wd,
    const float* __restrict__ bias,
    float* __restrict__ out, float* __restrict__ upd)
{
    int wid = threadIdx.x >> 6, lane = threadIdx.x & 63;
    int r = lane & 15, lg = lane >> 4;
    int g0 = blockIdx.x * 64 + wid * 16;
    int gp = g0 + r;
    int b = gp >> 14, p = gp & (HWSZ - 1);
    int i = p >> 7, j = p & 127;
    const short* xb = xt + ((size_t)(b << 14)) * XSTR + lg * 8;
    const float* mb = mask_in + (size_t)b * HWSZ;

    // hoisted offset/mask loads: 7 float4 = slots 0..27 (27 used)
    float ov[28];
    {
        const float4* op = (const float4*)(off_px + (size_t)gp * 32);
#pragma unroll
        for (int q = 0; q < 7; ++q) {
            float4 t = op[q];
            ov[4*q+0] = t.x; ov[4*q+1] = t.y; ov[4*q+2] = t.z; ov[4*q+3] = t.w;
        }
    }

    f32x4 acc0 = {0,0,0,0}, acc1 = {0,0,0,0}, acc2 = {0,0,0,0}, acc3 = {0,0,0,0};
    float um = 0.f;

    float rw[2][4], wgt[2][4], mbv[2][4];
    int   iofs[2][4];
    U4    abuf[2][4];

#define STATE(K, KB) do {                                                     \
        float dy = ov[2*(K)], dx = ov[2*(K)+1], m = ov[18+(K)];               \
        float py  = dy + (float)((K)/3 + i - 1);                              \
        float pxx = dx + (float)((K)%3 + j - 1);                              \
        float fy = floorf(py), fx = floorf(pxx);                              \
        float wy = py - fy, wx = pxx - fx;                                    \
        int y0 = (int)fy, x0 = (int)fx;                                       \
        int y1 = y0 + 1, x1 = x0 + 1;                                         \
        bool vy0 = (unsigned)y0 < HH, vy1 = (unsigned)y1 < HH;                \
        bool vx0 = (unsigned)x0 < WW, vx1 = (unsigned)x1 < WW;                \
        int yc0 = min(max(y0,0),HH-1), yc1 = min(max(y1,0),HH-1);             \
        int xc0 = min(max(x0,0),WW-1), xc1 = min(max(x1,0),WW-1);             \
        float r00 = (vy0 && vx0) ? (1.f-wy)*(1.f-wx) : 0.f;                   \
        float r01 = (vy0 && vx1) ? (1.f-wy)*wx : 0.f;                         \
        float r10 = (vy1 && vx0) ? wy*(1.f-wx) : 0.f;                         \
        float r11 = (vy1 && vx1) ? wy*wx : 0.f;                               \
        int i00 = yc0*WW+xc0, i01 = yc0*WW+xc1;                               \
        int i10 = yc1*WW+xc0, i11 = yc1*WW+xc1;                               \
        rw[KB][0]=r00; rw[KB][1]=r01; rw[KB][2]=r10; rw[KB][3]=r11;           \
        wgt[KB][0]=r00*m; wgt[KB][1]=r01*m; wgt[KB][2]=r10*m; wgt[KB][3]=r11*m;\
        iofs[KB][0]=i00*XSTR; iofs[KB][1]=i01*XSTR;                           \
        iofs[KB][2]=i10*XSTR; iofs[KB][3]=i11*XSTR;                           \
        mbv[KB][0]=mb[i00]; mbv[KB][1]=mb[i01];                               \
        mbv[KB][2]=mb[i10]; mbv[KB][3]=mb[i11];                               \
    } while (0)

    // prologue: tap 0 state + stage 0/1 gathers
    STATE(0, 0);
#pragma unroll
    for (int c = 0; c < 4; ++c)
        abuf[0][c].v = *(const uint4*)(xb + iofs[0][c]);
#pragma unroll
    for (int c = 0; c < 4; ++c)
        abuf[1][c].v = *(const uint4*)(xb + iofs[0][c] + 32);

#pragma unroll
    for (int s = 0; s < 18; ++s) {
        int k = s >> 1, ks = s & 1, kb = k & 1, sb = s & 1;

        // B fragments for this stage (L2-hot, covered by TLP)
        const bf16x8* wbk = wd + ((k * 2 + ks) * 4) * 64 + lane;
        bf16x8 B0 = wbk[0];
        bf16x8 B1 = wbk[64];
        bf16x8 B2 = wbk[128];
        bf16x8 B3 = wbk[192];

        // next-tap state (issues its mask gathers early)
        if (ks == 0 && k < 8) STATE(k + 1, (k + 1) & 1);

        // blend current stage's gathers into A fragment
        union { bf16x8 s8; unsigned u[4]; } A;
#pragma unroll
        for (int q = 0; q < 4; ++q) {
            unsigned d00 = abuf[sb][0].a[q], d01 = abuf[sb][1].a[q];
            unsigned d10 = abuf[sb][2].a[q], d11 = abuf[sb][3].a[q];
            float vlo = fmaf(wgt[kb][0], bflo(d00), fmaf(wgt[kb][1], bflo(d01),
                        fmaf(wgt[kb][2], bflo(d10), wgt[kb][3] * bflo(d11))));
            float vhi = fmaf(wgt[kb][0], bfhi(d00), fmaf(wgt[kb][1], bfhi(d01),
                        fmaf(wgt[kb][2], bfhi(d10), wgt[kb][3] * bfhi(d11))));
            A.u[q] = cvtpk(vlo, vhi);
        }

        if (ks == 1)
            um += rw[kb][0]*mbv[kb][0] + rw[kb][1]*mbv[kb][1]
                + rw[kb][2]*mbv[kb][2] + rw[kb][3]*mbv[kb][3];

        acc0 = __builtin_amdgcn_mfma_f32_16x16x32_bf16(A.s8, B0, acc0, 0, 0, 0);
        acc1 = __builtin_amdgcn_mfma_f32_16x16x32_bf16(A.s8, B1, acc1, 0, 0, 0);
        acc2 = __builtin_amdgcn_mfma_f32_16x16x32_bf16(A.s8, B2, acc2, 0, 0, 0);
        acc3 = __builtin_amdgcn_mfma_f32_16x16x32_bf16(A.s8, B3, acc3, 0, 0, 0);

        // refill this buffer for stage s+2
        if (s + 2 < 18) {
            int k2 = (s + 2) >> 1, ks2 = (s + 2) & 1, kb2 = k2 & 1;
#pragma unroll
            for (int c = 0; c < 4; ++c)
                abuf[sb][c].v = *(const uint4*)(xb + iofs[kb2][c] + ks2 * 32);
        }
    }
#undef STATE

    um = fminf(fmaxf(64.f * um, 0.f), 1.f);
    if (lane < 16) upd[g0 + lane] = um;

    int oc = lane & 15;
    int pr0 = lg * 4;
    float u[4];
#pragma unroll
    for (int rr = 0; rr < 4; ++rr) u[rr] = __shfl(um, pr0 + rr, 64);

#define STORE_NT(ACC, NT)                                                     \
    {                                                                         \
        float bo = bias[(NT) * 16 + oc];                                      \
        _Pragma("unroll")                                                     \
        for (int rr = 0; rr < 4; ++rr) {                                      \
            int gg = g0 + pr0 + rr;                                           \
            int bb = gg >> 14;                                                \
            int pp = gg & (HWSZ - 1);                                         \
            out[((size_t)(bb * 64 + (NT) * 16 + oc)) * HWSZ + pp] =           \
                (ACC[rr] + bo) * u[rr];                                       \
        }                                                                     \
    }
    STORE_NT(acc0, 0)
    STORE_NT(acc1, 1)
    STORE_NT(acc2, 2)
    STORE_NT(acc3, 3)
#undef STORE_NT
}

extern "C" void kernel_launch(void* const* d_in, const int* in_sizes, int n_in,
                              void* d_out, int out_size, void* d_ws, size_t ws_size,
                              hipStream_t stream) {
    const float* input    = (const float*)d_in[0];
    const float* mask_in  = (const float*)d_in[1];
    const float* weight   = (const float*)d_in[2];
    const float* bias     = (const float*)d_in[3];
    const float* offset_w = (const float*)d_in[4];
    const float* offset_b = (const float*)d_in[5];
    const float* mask_w   = (const float*)d_in[6];
    const float* mask_b   = (const float*)d_in[7];

    float* out = (float*)d_out;
    float* upd = out + (size_t)NB * COUT * HWSZ;

    float* ws     = (float*)d_ws;
    float* off_px = ws;                                  // 65536*32 f32 = 8.4 MB
    short* wd     = (short*)(off_px + (size_t)65536*32); // 36864 bf16
    short* wc     = wd + 36864;                          // 27648 bf16
    short* xt     = wc + 27648;                          // 65536*96 bf16 = 12.6 MB

    hipLaunchKernelGGL(prep_kernel, dim3(1168), dim3(256), 0, stream,
                       input, mask_in, weight, offset_w, mask_w, xt, wd, wc);
    hipLaunchKernelGGL(conv_offset_mfma, dim3(1024), dim3(256), 0, stream,
                       xt, (const bf16x8*)wc, offset_b, mask_b, off_px);
    hipLaunchKernelGGL(deform_main_mfma, dim3(1024), dim3(256), 0, stream,
                       xt, off_px, mask_in, (const bf16x8*)wd, bias, out, upd);
}